// Round 11
// baseline (104.762 us; speedup 1.0000x reference)
//
#include <hip/hip_runtime.h>
#include <math.h>

#define EPS 1e-8f

constexpr int B_ = 128;     // batch
constexpr int Q_ = 20;      // queries per sample
constexpr int D_ = 11;      // feature dim
constexpr int N_ = 100000;  // songs
constexpr int DP_ = 12;     // padded feature dim (3x float4 / 6x float2)
constexpr int NPAIR = B_ * Q_;  // 2560
constexpr int NCH = 1000;   // song chunks
constexpr int CS = N_ / NCH;    // 100 songs per chunk
constexpr int NG = CS / 4;      // 25 4-song groups per chunk
constexpr int TPB = 128;
constexpr int PPT = 4;      // pairs per thread (A,B,C,D)
constexpr int REP = NPAIR / (PPT * TPB);   // 5 pair-blocks
constexpr int CPB = 2;      // chunks per block (write-late double buffer)
constexpr int NPB = NCH / CPB;             // 500 chunk-pairs
constexpr int MPAD = (NPB + 7) / 8;        // 63
constexpr int SGRID = 8 * MPAD * REP;      // 2520 (20 guard blocks)

typedef __attribute__((ext_vector_type(2))) float f2;

__device__ __forceinline__ f2 lo2(float4 v) { f2 r; r.x = v.x; r.y = v.y; return r; }
__device__ __forceinline__ f2 hi2(float4 v) { f2 r; r.x = v.z; r.y = v.w; return r; }

// packed dot over 12 dims (dim 11 zero-padded on both sides):
// 1 v_pk_mul + 5 v_pk_fma + 1 v_add. Identical sequence at every call site
// (bit-exact recompute for the tie-break).
__device__ __forceinline__ float dot12(f2 q0, f2 q1, f2 q2, f2 q3, f2 q4, f2 q5,
                                       f2 s0, f2 s1, f2 s2, f2 s3, f2 s4, f2 s5)
{
    f2 a = q0 * s0;
    a = q1 * s1 + a;
    a = q2 * s2 + a;
    a = q3 * s3 + a;
    a = q4 * s4 + a;
    a = q5 * s5 + a;
    return a.x + a.y;
}

// ---------------- fused prep: MLP encoder + song pre-normalization ---------------
__global__ void prep_kernel(const float* __restrict__ x,
                            const float* __restrict__ W1, const float* __restrict__ b1,
                            const float* __restrict__ W2, const float* __restrict__ b2,
                            const float* __restrict__ W3, const float* __restrict__ b3,
                            const float* __restrict__ songs,
                            float* __restrict__ pnorm, float* __restrict__ snorm,
                            int do_snorm)
{
    const int t = threadIdx.x;
    if (blockIdx.x >= B_) {
        if (!do_snorm) return;
        const int i = (blockIdx.x - B_) * blockDim.x + t;
        if (i >= N_) return;
        float v[DP_]; float ss = 0.0f;
#pragma unroll
        for (int d = 0; d < D_; ++d) { v[d] = songs[(size_t)i * D_ + d]; ss += v[d] * v[d]; }
        float nrm = fmaxf(sqrtf(ss), EPS);
#pragma unroll
        for (int d = 0; d < D_; ++d) v[d] /= nrm;
        v[D_] = 0.0f;
        float4* o = reinterpret_cast<float4*>(snorm + (size_t)i * DP_);
        o[0] = make_float4(v[0], v[1], v[2], v[3]);
        o[1] = make_float4(v[4], v[5], v[6], v[7]);
        o[2] = make_float4(v[8], v[9], v[10], v[11]);
        return;
    }
    __shared__ float xr[55];
    __shared__ float h1[128];
    __shared__ float h2[64];
    __shared__ float prod[220];
    const int b = blockIdx.x;
    if (t < 55) xr[t] = x[b * 55 + t];
    __syncthreads();
    if (t < 128) {
        float s = b1[t];
        for (int k = 0; k < 55; ++k) s += xr[k] * W1[k * 128 + t];
        h1[t] = fmaxf(s, 0.0f);
    }
    __syncthreads();
    if (t < 64) {
        float s = b2[t];
        for (int k = 0; k < 128; ++k) s += h1[k] * W2[k * 64 + t];
        h2[t] = fmaxf(s, 0.0f);
    }
    __syncthreads();
    if (t < 220) {
        float s = b3[t];
        for (int k = 0; k < 64; ++k) s += h2[k] * W3[k * 220 + t];
        prod[t] = s;
    }
    __syncthreads();
    if (t < Q_) {
        float ss = 0.0f;
        for (int d = 0; d < D_; ++d) { float v = prod[t * D_ + d]; ss += v * v; }
        float nrm = fmaxf(sqrtf(ss), EPS);
        float* o = pnorm + (b * Q_ + t) * DP_;
        for (int d = 0; d < D_; ++d) o[d] = prod[t * D_ + d] / nrm;
        o[D_] = 0.0f;
    }
}

// monotone float -> uint32 (strictly order-preserving for non-NaN)
__device__ __forceinline__ unsigned int fkey(float f)
{
    unsigned int b = __float_as_uint(f);
    return (b & 0x80000000u) ? ~b : (b | 0x80000000u);
}

// pack (value, index): high = monotone value, low = ~idx so that for equal values
// atomicMax keeps the SMALLER index (numpy first-index argmax semantics)
__device__ __forceinline__ unsigned long long pack_vi(float v, int idx)
{
    return ((unsigned long long)fkey(v) << 32) | (unsigned long long)(0xFFFFFFFFu - (unsigned int)idx);
}

#define QARGS(P) q##P##0, q##P##1, q##P##2, q##P##3, q##P##4, q##P##5

#define PMAX(P, GCUR) { \
    float d0 = dot12(QARGS(P), lo2(s0), hi2(s0), lo2(s1),  hi2(s1),  lo2(s2),  hi2(s2));  \
    float d1 = dot12(QARGS(P), lo2(s3), hi2(s3), lo2(s4),  hi2(s4),  lo2(s5),  hi2(s5));  \
    float d2 = dot12(QARGS(P), lo2(s6), hi2(s6), lo2(s7),  hi2(s7),  lo2(s8),  hi2(s8));  \
    float d3 = dot12(QARGS(P), lo2(s9), hi2(s9), lo2(s10), hi2(s10), lo2(s11), hi2(s11)); \
    float mx = fmaxf(fmaxf(d0, d1), fmaxf(d2, d3)); \
    if (mx > bv##P) { bv##P = mx; gi##P = (GCUR); } \
}

#define GSTEP(L4, G, GOFF) { \
    const float4* vg = (L4) + (G) * 12; \
    float4 s0 = vg[0], s1 = vg[1], s2  = vg[2],  s3  = vg[3],  s4  = vg[4],  s5  = vg[5]; \
    float4 s6 = vg[6], s7 = vg[7], s8  = vg[8],  s9  = vg[9],  s10 = vg[10], s11 = vg[11]; \
    PMAX(A, (GOFF) + (G)) PMAX(B, (GOFF) + (G)) PMAX(C, (GOFF) + (G)) PMAX(D, (GOFF) + (G)) \
}

#define QPIN() asm volatile("" : \
    "+v"(qA0), "+v"(qA1), "+v"(qA2), "+v"(qA3), "+v"(qA4), "+v"(qA5), \
    "+v"(qB0), "+v"(qB1), "+v"(qB2), "+v"(qB3), "+v"(qB4), "+v"(qB5), \
    "+v"(qC0), "+v"(qC1), "+v"(qC2), "+v"(qC3), "+v"(qC4), "+v"(qC5), \
    "+v"(qD0), "+v"(qD1), "+v"(qD2), "+v"(qD3), "+v"(qD4), "+v"(qD5))

#define FINI(P, POFF) { \
    int gsel = gi##P; \
    int cs = (gsel >= NG) ? 1 : 0; \
    int gg = gsel - cs * NG; \
    const float4* vg = reinterpret_cast<const float4*>(lds[cs]) + gg * 12; \
    float4 s0 = vg[0], s1 = vg[1], s2  = vg[2],  s3  = vg[3],  s4  = vg[4],  s5  = vg[5]; \
    float4 s6 = vg[6], s7 = vg[7], s8  = vg[8],  s9  = vg[9],  s10 = vg[10], s11 = vg[11]; \
    float d0 = dot12(QARGS(P), lo2(s0), hi2(s0), lo2(s1),  hi2(s1),  lo2(s2),  hi2(s2));  \
    float d1 = dot12(QARGS(P), lo2(s3), hi2(s3), lo2(s4),  hi2(s4),  lo2(s5),  hi2(s5));  \
    float d2 = dot12(QARGS(P), lo2(s6), hi2(s6), lo2(s7),  hi2(s7),  lo2(s8),  hi2(s8));  \
    float d3 = dot12(QARGS(P), lo2(s9), hi2(s9), lo2(s10), hi2(s10), lo2(s11), hi2(s11)); \
    int base = (c0 + cs) * CS + gg * 4; \
    int idx = base; \
    if (d3 == bv##P) idx = base + 3; \
    if (d2 == bv##P) idx = base + 2; \
    if (d1 == bv##P) idx = base + 1; \
    if (d0 == bv##P) idx = base; \
    atomicMax(&res[jb + (POFF) * TPB], pack_vi(bv##P, idx)); \
}

// ---------------- sim + global argmax: pinned queries, packed fp32, 2 chunks ------
// XCD-swizzled 1-D grid: bid -> (u=bid&7 fixed XCD, r=pair-block, cpair=u+8*m).
// Chunk pair staged in LDS (c1 write-late); group loop reads broadcast
// ds_read_b128 + pk-fma. Empty asm pins the 24 query f2s in VGPRs every
// iteration -> compiler cannot demote/rematerialize them.
__global__ __launch_bounds__(TPB, 2)
void sim11_kernel(const float* __restrict__ pnorm,
                  const float* __restrict__ snorm,
                  unsigned long long* __restrict__ res)
{
    __shared__ __align__(16) float lds[CPB][CS * DP_];   // 2 x 4800 B
    const int bid = blockIdx.x;
    const int u = bid & 7;
    const int kk = bid >> 3;
    const int r = kk % REP;
    const int m = kk / REP;
    const int cpair = u + 8 * m;
    if (cpair >= NPB) return;                  // guard (500 % 8 != 0)
    const int t = threadIdx.x;
    const int c0 = cpair * CPB;

    const float4* s40 = reinterpret_cast<const float4*>(snorm) + (size_t)c0 * CS * 3;
    const float4* s41 = s40 + CS * 3;
    float4* b0 = reinterpret_cast<float4*>(lds[0]);
    float4* b1 = reinterpret_cast<float4*>(lds[1]);

    // stage chunk c0 (300 float4s)
    b0[t] = s40[t];
    b0[t + TPB] = s40[t + TPB];
    if (t < CS * 3 - 2 * TPB) b0[t + 2 * TPB] = s40[t + 2 * TPB];
    // issue chunk c1 loads now; LDS write deferred until after c0 compute
    float4 r0 = s41[t];
    float4 r1 = s41[t + TPB];
    float4 r2 = make_float4(0.f, 0.f, 0.f, 0.f);
    if (t < CS * 3 - 2 * TPB) r2 = s41[t + 2 * TPB];

    // 4 query vectors as 24 NAMED f2 registers (no arrays -> nothing to demote)
    const int jb = r * (PPT * TPB) + t;
    const float4* qp;
    qp = reinterpret_cast<const float4*>(pnorm + (size_t)(jb + 0 * TPB) * DP_);
    float4 qa = qp[0], qb = qp[1], qc = qp[2];
    f2 qA0 = lo2(qa), qA1 = hi2(qa), qA2 = lo2(qb), qA3 = hi2(qb), qA4 = lo2(qc), qA5 = hi2(qc);
    qp = reinterpret_cast<const float4*>(pnorm + (size_t)(jb + 1 * TPB) * DP_);
    qa = qp[0]; qb = qp[1]; qc = qp[2];
    f2 qB0 = lo2(qa), qB1 = hi2(qa), qB2 = lo2(qb), qB3 = hi2(qb), qB4 = lo2(qc), qB5 = hi2(qc);
    qp = reinterpret_cast<const float4*>(pnorm + (size_t)(jb + 2 * TPB) * DP_);
    qa = qp[0]; qb = qp[1]; qc = qp[2];
    f2 qC0 = lo2(qa), qC1 = hi2(qa), qC2 = lo2(qb), qC3 = hi2(qb), qC4 = lo2(qc), qC5 = hi2(qc);
    qp = reinterpret_cast<const float4*>(pnorm + (size_t)(jb + 3 * TPB) * DP_);
    qa = qp[0]; qb = qp[1]; qc = qp[2];
    f2 qD0 = lo2(qa), qD1 = hi2(qa), qD2 = lo2(qb), qD3 = hi2(qb), qD4 = lo2(qc), qD5 = hi2(qc);
    __syncthreads();

    float bvA = -1e30f, bvB = -1e30f, bvC = -1e30f, bvD = -1e30f;
    int giA = 0, giB = 0, giC = 0, giD = 0;

    for (int g = 0; g < NG; ++g) {
        QPIN();
        GSTEP(b0, g, 0);
    }

    // write-late: c1 data arrived long ago; store + barrier, then compute
    b1[t] = r0;
    b1[t + TPB] = r1;
    if (t < CS * 3 - 2 * TPB) b1[t + 2 * TPB] = r2;
    __syncthreads();

    for (int g = 0; g < NG; ++g) {
        QPIN();
        GSTEP(b1, g, NG);
    }

    // Recompute winning group with the identical packed sequence -> bit-exact;
    // descending cascade picks the FIRST in-group index achieving the max.
    FINI(A, 0) FINI(B, 1) FINI(C, 2) FINI(D, 3)
}

// ---------------- fallback (no snorm workspace): global loads, on-the-fly norm ----
template<int FNCH>
__global__ void sim6f_kernel(const float* __restrict__ pnorm,
                             const float* __restrict__ songs,
                             unsigned long long* __restrict__ res)
{
    constexpr int FCS = N_ / FNCH;
    const int chunk = blockIdx.x;
    const int j = blockIdx.y * 256 + threadIdx.x;

    float qv[D_];
#pragma unroll
    for (int d = 0; d < D_; ++d) qv[d] = pnorm[j * DP_ + d];

    float bestv = -1e30f;
    int   besti = 0;
    const int base = chunk * FCS;
    for (int i = base; i < base + FCS; ++i) {
        float sv[D_]; float ss = 0.0f;
#pragma unroll
        for (int d = 0; d < D_; ++d) { sv[d] = songs[(size_t)i * D_ + d]; ss += sv[d] * sv[d]; }
        float nrm = fmaxf(sqrtf(ss), EPS);
        float a = qv[0] * (sv[0] / nrm);
#pragma unroll
        for (int d = 1; d < D_; ++d) a = fmaf(qv[d], sv[d] / nrm, a);
        if (a > bestv) { bestv = a; besti = i; }
    }
    atomicMax(&res[j], pack_vi(bestv, besti));
}

// ---------------- decode + gather ------------------------------------------------
__global__ void gather_kernel(const unsigned long long* __restrict__ res,
                              const float* __restrict__ songs, float* __restrict__ out)
{
    const int j = blockIdx.x * blockDim.x + threadIdx.x;
    if (j >= NPAIR) return;
    const unsigned int idx = 0xFFFFFFFFu - (unsigned int)(res[j] & 0xFFFFFFFFull);
#pragma unroll
    for (int d = 0; d < D_; ++d) out[(size_t)j * D_ + d] = songs[(size_t)idx * D_ + d];
}

extern "C" void kernel_launch(void* const* d_in, const int* in_sizes, int n_in,
                              void* d_out, int out_size, void* d_ws, size_t ws_size,
                              hipStream_t stream)
{
    const float* x     = (const float*)d_in[0];
    const float* W1    = (const float*)d_in[1];
    const float* b1    = (const float*)d_in[2];
    const float* W2    = (const float*)d_in[3];
    const float* b2    = (const float*)d_in[4];
    const float* W3    = (const float*)d_in[5];
    const float* b3    = (const float*)d_in[6];
    const float* songs = (const float*)d_in[7];
    float* out = (float*)d_out;

    constexpr size_t PN = (size_t)NPAIR * DP_;      // pnorm floats
    constexpr size_t SN = (size_t)N_ * DP_;         // snorm floats
    float* pnorm = (float*)d_ws;
    constexpr int SNB = (N_ + 255) / 256;

    const size_t need_full = (PN + SN) * sizeof(float) + (size_t)NPAIR * 8 + 64;
    const size_t need_min  = PN * sizeof(float) + (size_t)NPAIR * 8 + 64;

    if (ws_size >= need_full) {
        float* snorm = pnorm + PN;
        unsigned long long* res =
            (unsigned long long*)(((uintptr_t)(snorm + SN) + 7) & ~(uintptr_t)7);
        hipMemsetAsync(res, 0, (size_t)NPAIR * 8, stream);
        prep_kernel<<<B_ + SNB, 256, 0, stream>>>(x, W1, b1, W2, b2, W3, b3, songs,
                                                  pnorm, snorm, 1);
        sim11_kernel<<<SGRID, TPB, 0, stream>>>(pnorm, snorm, res);
        gather_kernel<<<(NPAIR + 255) / 256, 256, 0, stream>>>(res, songs, out);
    } else if (ws_size >= need_min) {
        unsigned long long* res =
            (unsigned long long*)(((uintptr_t)(pnorm + PN) + 7) & ~(uintptr_t)7);
        hipMemsetAsync(res, 0, (size_t)NPAIR * 8, stream);
        prep_kernel<<<B_, 256, 0, stream>>>(x, W1, b1, W2, b2, W3, b3, songs,
                                            pnorm, nullptr, 0);
        constexpr int FNCH = 250;
        sim6f_kernel<FNCH><<<dim3(FNCH, NPAIR / 256), 256, 0, stream>>>(pnorm, songs, res);
        gather_kernel<<<(NPAIR + 255) / 256, 256, 0, stream>>>(res, songs, out);
    }
}

// Round 13
// 91.690 us; speedup vs baseline: 1.1426x; 1.1426x over previous
//
#include <hip/hip_runtime.h>
#include <math.h>

#define EPS 1e-8f

constexpr int B_ = 128;     // batch
constexpr int Q_ = 20;      // queries per sample
constexpr int D_ = 11;      // feature dim
constexpr int N_ = 100000;  // songs
constexpr int DP_ = 12;     // padded feature dim (3x float4)
constexpr int NPAIR = B_ * Q_;  // 2560
constexpr int NCH = 1000;   // song chunks
constexpr int CS = N_ / NCH;    // 100 songs per chunk
constexpr int NG = CS / 4;      // 25 4-song groups per chunk
constexpr int TPB = 128;
constexpr int PPT = 4;      // pairs per thread (A,B,C,D)
constexpr int REP = NPAIR / (PPT * TPB);   // 5 pair-blocks
constexpr int CPB = 2;      // chunks per block (write-late double buffer)
constexpr int NPB = NCH / CPB;             // 500 chunk-pairs
constexpr int MPAD = (NPB + 7) / 8;        // 63
constexpr int SGRID = 8 * MPAD * REP;      // 2520 (guards for 500 % 8 != 0)

typedef __attribute__((ext_vector_type(4))) float f4;

// ---------------- fused prep: MLP encoder + song pre-normalization ---------------
__global__ void prep_kernel(const float* __restrict__ x,
                            const float* __restrict__ W1, const float* __restrict__ b1,
                            const float* __restrict__ W2, const float* __restrict__ b2,
                            const float* __restrict__ W3, const float* __restrict__ b3,
                            const float* __restrict__ songs,
                            float* __restrict__ pnorm, float* __restrict__ snorm,
                            int do_snorm)
{
    const int t = threadIdx.x;
    if (blockIdx.x >= B_) {
        if (!do_snorm) return;
        const int i = (blockIdx.x - B_) * blockDim.x + t;
        if (i >= N_) return;
        float v[DP_]; float ss = 0.0f;
#pragma unroll
        for (int d = 0; d < D_; ++d) { v[d] = songs[(size_t)i * D_ + d]; ss += v[d] * v[d]; }
        float nrm = fmaxf(sqrtf(ss), EPS);
#pragma unroll
        for (int d = 0; d < D_; ++d) v[d] /= nrm;
        v[D_] = 0.0f;
        float4* o = reinterpret_cast<float4*>(snorm + (size_t)i * DP_);
        o[0] = make_float4(v[0], v[1], v[2], v[3]);
        o[1] = make_float4(v[4], v[5], v[6], v[7]);
        o[2] = make_float4(v[8], v[9], v[10], v[11]);
        return;
    }
    __shared__ float xr[55];
    __shared__ float h1[128];
    __shared__ float h2[64];
    __shared__ float prod[220];
    const int b = blockIdx.x;
    if (t < 55) xr[t] = x[b * 55 + t];
    __syncthreads();
    if (t < 128) {
        float s = b1[t];
        for (int k = 0; k < 55; ++k) s += xr[k] * W1[k * 128 + t];
        h1[t] = fmaxf(s, 0.0f);
    }
    __syncthreads();
    if (t < 64) {
        float s = b2[t];
        for (int k = 0; k < 128; ++k) s += h1[k] * W2[k * 64 + t];
        h2[t] = fmaxf(s, 0.0f);
    }
    __syncthreads();
    if (t < 220) {
        float s = b3[t];
        for (int k = 0; k < 64; ++k) s += h2[k] * W3[k * 220 + t];
        prod[t] = s;
    }
    __syncthreads();
    if (t < Q_) {
        float ss = 0.0f;
        for (int d = 0; d < D_; ++d) { float v = prod[t * D_ + d]; ss += v * v; }
        float nrm = fmaxf(sqrtf(ss), EPS);
        float* o = pnorm + (b * Q_ + t) * DP_;
        for (int d = 0; d < D_; ++d) o[d] = prod[t * D_ + d] / nrm;
        o[D_] = 0.0f;
    }
}

// dot over 11 dims, fixed fmaf sequence (deterministic, identical at every call site)
__device__ __forceinline__ float dot11v(f4 qa, f4 qb, f4 qc,
                                        float4 a, float4 b, float4 c)
{
    float x = qa.x * a.x;
    x = fmaf(qa.y, a.y, x);
    x = fmaf(qa.z, a.z, x);
    x = fmaf(qa.w, a.w, x);
    x = fmaf(qb.x, b.x, x);
    x = fmaf(qb.y, b.y, x);
    x = fmaf(qb.z, b.z, x);
    x = fmaf(qb.w, b.w, x);
    x = fmaf(qc.x, c.x, x);
    x = fmaf(qc.y, c.y, x);
    x = fmaf(qc.z, c.z, x);
    return x;
}

// monotone float -> uint32 (strictly order-preserving for non-NaN)
__device__ __forceinline__ unsigned int fkey(float f)
{
    unsigned int b = __float_as_uint(f);
    return (b & 0x80000000u) ? ~b : (b | 0x80000000u);
}

// pack (value, index): high = monotone value, low = ~idx so that for equal values
// atomicMax keeps the SMALLER index (numpy first-index argmax semantics)
__device__ __forceinline__ unsigned long long pack_vi(float v, int idx)
{
    return ((unsigned long long)fkey(v) << 32) | (unsigned long long)(0xFFFFFFFFu - (unsigned int)idx);
}

// Inline-asm query load: asm outputs CANNOT be rematerialized by the register
// allocator -> the 12 float4s stay resident (or spill, which the allocator avoids
// under a 256-VGPR budget). EARLY-CLOBBER (=&v) is mandatory: without it the
// first load's dest may alias the address pair and corrupt it (round-12 crash).
#define QLOAD(P, PTR) \
    asm volatile("global_load_dwordx4 %0, %3, off\n\t" \
                 "global_load_dwordx4 %1, %3, off offset:16\n\t" \
                 "global_load_dwordx4 %2, %3, off offset:32" \
                 : "=&v"(q##P##a), "=&v"(q##P##b), "=&v"(q##P##c) \
                 : "v"(PTR) : "memory")

// s_waitcnt with all 12 vectors as in/outs: every consumer is data-dependent on
// this asm, so no use can be scheduled before the wait.
#define QWAIT() \
    asm volatile("s_waitcnt vmcnt(0)" \
                 : "+v"(qAa), "+v"(qAb), "+v"(qAc), "+v"(qBa), "+v"(qBb), "+v"(qBc), \
                   "+v"(qCa), "+v"(qCb), "+v"(qCc), "+v"(qDa), "+v"(qDb), "+v"(qDc) \
                 :: "memory")

#define PMAXV(P, G) { \
    float d0 = dot11v(q##P##a, q##P##b, q##P##c, s0, s1,  s2);  \
    float d1 = dot11v(q##P##a, q##P##b, q##P##c, s3, s4,  s5);  \
    float d2 = dot11v(q##P##a, q##P##b, q##P##c, s6, s7,  s8);  \
    float d3 = dot11v(q##P##a, q##P##b, q##P##c, s9, s10, s11); \
    float mx = fmaxf(fmaxf(d0, d1), fmaxf(d2, d3)); \
    if (mx > bv##P) { bv##P = mx; gi##P = (G); } \
}

#define GSTEP(L4, G, GOFF) { \
    const float4* vg = (L4) + (G) * 12; \
    float4 s0 = vg[0], s1 = vg[1], s2  = vg[2],  s3  = vg[3],  s4  = vg[4],  s5  = vg[5]; \
    float4 s6 = vg[6], s7 = vg[7], s8  = vg[8],  s9  = vg[9],  s10 = vg[10], s11 = vg[11]; \
    PMAXV(A, (GOFF) + (G)) PMAXV(B, (GOFF) + (G)) PMAXV(C, (GOFF) + (G)) PMAXV(D, (GOFF) + (G)) \
}

#define FINI(P, POFF) { \
    int gsel = gi##P; \
    int cs = (gsel >= NG) ? 1 : 0; \
    int gg = gsel - cs * NG; \
    const float4* vg = reinterpret_cast<const float4*>(lds[cs]) + gg * 12; \
    float4 s0 = vg[0], s1 = vg[1], s2  = vg[2],  s3  = vg[3],  s4  = vg[4],  s5  = vg[5]; \
    float4 s6 = vg[6], s7 = vg[7], s8  = vg[8],  s9  = vg[9],  s10 = vg[10], s11 = vg[11]; \
    float d0 = dot11v(q##P##a, q##P##b, q##P##c, s0, s1,  s2);  \
    float d1 = dot11v(q##P##a, q##P##b, q##P##c, s3, s4,  s5);  \
    float d2 = dot11v(q##P##a, q##P##b, q##P##c, s6, s7,  s8);  \
    float d3 = dot11v(q##P##a, q##P##b, q##P##c, s9, s10, s11); \
    int base = (c0 + cs) * CS + gg * 4; \
    int idx = base; \
    if (d3 == bv##P) idx = base + 3; \
    if (d2 == bv##P) idx = base + 2; \
    if (d1 == bv##P) idx = base + 1; \
    if (d0 == bv##P) idx = base; \
    atomicMax(&res[jb + (POFF) * TPB], pack_vi(bv##P, idx)); \
}

// ---------------- sim + global argmax: asm-pinned queries, LDS chunks -------------
// XCD-swizzled 1-D grid: bid -> (u=bid&7 fixed XCD, r=pair-block, cpair=u+8*m).
// Two chunks per block, c1 write-late (loads issued early, LDS-written after c0's
// compute). Group loop: 12 uniform ds_read_b128 per 176 FMA, zero global traffic.
__global__ __launch_bounds__(TPB, 2)
void sim13_kernel(const float* __restrict__ pnorm,
                  const float* __restrict__ snorm,
                  unsigned long long* __restrict__ res)
{
    __shared__ __align__(16) float lds[CPB][CS * DP_];   // 2 x 4800 B
    const int bid = blockIdx.x;
    const int u = bid & 7;
    const int kk = bid >> 3;
    const int r = kk % REP;
    const int m = kk / REP;
    const int cpair = u + 8 * m;
    if (cpair >= NPB) return;                  // guard (500 % 8 != 0)
    const int t = threadIdx.x;
    const int c0 = cpair * CPB;

    const float4* s40 = reinterpret_cast<const float4*>(snorm) + (size_t)c0 * CS * 3;
    const float4* s41 = s40 + CS * 3;
    float4* b0 = reinterpret_cast<float4*>(lds[0]);
    float4* b1 = reinterpret_cast<float4*>(lds[1]);

    // stage chunk c0 (300 float4s)
    b0[t] = s40[t];
    b0[t + TPB] = s40[t + TPB];
    if (t < CS * 3 - 2 * TPB) b0[t + 2 * TPB] = s40[t + 2 * TPB];

    // query loads via inline asm (un-rematerializable)
    const int jb = r * (PPT * TPB) + t;
    f4 qAa, qAb, qAc, qBa, qBb, qBc, qCa, qCb, qCc, qDa, qDb, qDc;
    {
        const float* qp0 = pnorm + (size_t)(jb + 0 * TPB) * DP_;
        const float* qp1 = pnorm + (size_t)(jb + 1 * TPB) * DP_;
        const float* qp2 = pnorm + (size_t)(jb + 2 * TPB) * DP_;
        const float* qp3 = pnorm + (size_t)(jb + 3 * TPB) * DP_;
        QLOAD(A, qp0);
        QLOAD(B, qp1);
        QLOAD(C, qp2);
        QLOAD(D, qp3);
    }
    QWAIT();

    // issue chunk c1 loads now; LDS write deferred until after c0 compute
    float4 r0 = s41[t];
    float4 r1 = s41[t + TPB];
    float4 r2 = make_float4(0.f, 0.f, 0.f, 0.f);
    if (t < CS * 3 - 2 * TPB) r2 = s41[t + 2 * TPB];

    __syncthreads();

    float bvA = -1e30f, bvB = -1e30f, bvC = -1e30f, bvD = -1e30f;
    int giA = 0, giB = 0, giC = 0, giD = 0;

    for (int g = 0; g < NG; ++g) {
        GSTEP(b0, g, 0);
    }

    // write-late: c1 data arrived long ago; store + barrier, then compute
    b1[t] = r0;
    b1[t + TPB] = r1;
    if (t < CS * 3 - 2 * TPB) b1[t + 2 * TPB] = r2;
    __syncthreads();

    for (int g = 0; g < NG; ++g) {
        GSTEP(b1, g, NG);
    }

    // Recompute winning group with the identical fmaf sequence -> bit-exact;
    // descending cascade picks the FIRST in-group index achieving the max.
    FINI(A, 0) FINI(B, 1) FINI(C, 2) FINI(D, 3)
}

// ---------------- fallback (no snorm workspace): global loads, on-the-fly norm ----
template<int FNCH>
__global__ void sim6f_kernel(const float* __restrict__ pnorm,
                             const float* __restrict__ songs,
                             unsigned long long* __restrict__ res)
{
    constexpr int FCS = N_ / FNCH;
    const int chunk = blockIdx.x;
    const int j = blockIdx.y * 256 + threadIdx.x;

    float qv[D_];
#pragma unroll
    for (int d = 0; d < D_; ++d) qv[d] = pnorm[j * DP_ + d];

    float bestv = -1e30f;
    int   besti = 0;
    const int base = chunk * FCS;
    for (int i = base; i < base + FCS; ++i) {
        float sv[D_]; float ss = 0.0f;
#pragma unroll
        for (int d = 0; d < D_; ++d) { sv[d] = songs[(size_t)i * D_ + d]; ss += sv[d] * sv[d]; }
        float nrm = fmaxf(sqrtf(ss), EPS);
        float a = qv[0] * (sv[0] / nrm);
#pragma unroll
        for (int d = 1; d < D_; ++d) a = fmaf(qv[d], sv[d] / nrm, a);
        if (a > bestv) { bestv = a; besti = i; }
    }
    atomicMax(&res[j], pack_vi(bestv, besti));
}

// ---------------- decode + gather ------------------------------------------------
__global__ void gather_kernel(const unsigned long long* __restrict__ res,
                              const float* __restrict__ songs, float* __restrict__ out)
{
    const int j = blockIdx.x * blockDim.x + threadIdx.x;
    if (j >= NPAIR) return;
    const unsigned int idx = 0xFFFFFFFFu - (unsigned int)(res[j] & 0xFFFFFFFFull);
#pragma unroll
    for (int d = 0; d < D_; ++d) out[(size_t)j * D_ + d] = songs[(size_t)idx * D_ + d];
}

extern "C" void kernel_launch(void* const* d_in, const int* in_sizes, int n_in,
                              void* d_out, int out_size, void* d_ws, size_t ws_size,
                              hipStream_t stream)
{
    const float* x     = (const float*)d_in[0];
    const float* W1    = (const float*)d_in[1];
    const float* b1    = (const float*)d_in[2];
    const float* W2    = (const float*)d_in[3];
    const float* b2    = (const float*)d_in[4];
    const float* W3    = (const float*)d_in[5];
    const float* b3    = (const float*)d_in[6];
    const float* songs = (const float*)d_in[7];
    float* out = (float*)d_out;

    constexpr size_t PN = (size_t)NPAIR * DP_;      // pnorm floats
    constexpr size_t SN = (size_t)N_ * DP_;         // snorm floats
    float* pnorm = (float*)d_ws;
    constexpr int SNB = (N_ + 255) / 256;

    const size_t need_full = (PN + SN) * sizeof(float) + (size_t)NPAIR * 8 + 64;
    const size_t need_min  = PN * sizeof(float) + (size_t)NPAIR * 8 + 64;

    if (ws_size >= need_full) {
        float* snorm = pnorm + PN;
        unsigned long long* res =
            (unsigned long long*)(((uintptr_t)(snorm + SN) + 7) & ~(uintptr_t)7);
        hipMemsetAsync(res, 0, (size_t)NPAIR * 8, stream);
        prep_kernel<<<B_ + SNB, 256, 0, stream>>>(x, W1, b1, W2, b2, W3, b3, songs,
                                                  pnorm, snorm, 1);
        sim13_kernel<<<SGRID, TPB, 0, stream>>>(pnorm, snorm, res);
        gather_kernel<<<(NPAIR + 255) / 256, 256, 0, stream>>>(res, songs, out);
    } else if (ws_size >= need_min) {
        unsigned long long* res =
            (unsigned long long*)(((uintptr_t)(pnorm + PN) + 7) & ~(uintptr_t)7);
        hipMemsetAsync(res, 0, (size_t)NPAIR * 8, stream);
        prep_kernel<<<B_, 256, 0, stream>>>(x, W1, b1, W2, b2, W3, b3, songs,
                                            pnorm, nullptr, 0);
        constexpr int FNCH = 250;
        sim6f_kernel<FNCH><<<dim3(FNCH, NPAIR / 256), 256, 0, stream>>>(pnorm, songs, res);
        gather_kernel<<<(NPAIR + 255) / 256, 256, 0, stream>>>(res, songs, out);
    }
}